// Round 20
// baseline (187.184 us; speedup 1.0000x reference)
//
#include <hip/hip_runtime.h>
#include <hip/hip_bf16.h>
#include <math.h>

#define BB 64
#define SS 2048
#define HH 512
#define VV 50257
#define KD 1024    // I + H
#define NSPLIT 32  // attn s-chunks per batch row
#define NTILE 786  // ceil(VV/64)

typedef float f32x4 __attribute__((ext_vector_type(4)));
typedef __bf16 bf16x8 __attribute__((ext_vector_type(8)));
typedef __attribute__((address_space(3))) void lds_void;
typedef __attribute__((address_space(1))) const void glb_void;

__device__ __forceinline__ float dot4(float4 a, float4 b) {
  return a.x*b.x + a.y*b.y + a.z*b.z + a.w*b.w;
}

__device__ __forceinline__ bf16x8 cvt8(float4 a, float4 b) {
  bf16x8 r;
  r[0]=(__bf16)a.x; r[1]=(__bf16)a.y; r[2]=(__bf16)a.z; r[3]=(__bf16)a.w;
  r[4]=(__bf16)b.x; r[5]=(__bf16)b.y; r[6]=(__bf16)b.z; r[7]=(__bf16)b.w;
  return r;
}

// featA fragment-linear layout: element (b, k) lives at
//   (k>>5)*2048 + (b>>4)*512 + ((k>>3)&3)*128 + (b&15)*8 + (k&7)
__device__ __forceinline__ size_t fragAddr(int b, int k) {
  return (size_t)(k >> 5)*2048 + (size_t)(b >> 4)*512
       + (size_t)((k >> 3) & 3)*128 + (size_t)(b & 15)*8 + (size_t)(k & 7);
}

// ---------------------------------------------------------------------------
// Kernel A: attention partials (R14 proven; R15-measured ~44us).
// ---------------------------------------------------------------------------
__global__ __launch_bounds__(256) void attn_partial(
    const float* __restrict__ hprev, const float* __restrict__ enc,
    float* __restrict__ pm, float* __restrict__ pl, float* __restrict__ pacc)
{
  const int b = blockIdx.x >> 5;
  const int split = blockIdx.x & 31;
  const int t = threadIdx.x;
  const int w = t >> 6, lane = t & 63;

  const float* hb = hprev + b*HH + lane*8;
  const float4 h0 = *(const float4*)hb;
  const float4 h1 = *(const float4*)(hb + 4);
  const int s0 = split*64 + w*16;

  float m = -INFINITY, lsum = 0.f;
  float acc[8];
#pragma unroll
  for (int j = 0; j < 8; ++j) acc[j] = 0.f;

#pragma unroll 1
  for (int half = 0; half < 2; ++half) {
    float4 ea[8], eb[8];
#pragma unroll
    for (int i = 0; i < 8; ++i) {
      const float* ep = enc + ((size_t)(s0 + half*8 + i)*BB + b)*HH + lane*8;
      ea[i] = *(const float4*)ep; eb[i] = *(const float4*)(ep + 4);
    }
    float dd[8];
#pragma unroll
    for (int i = 0; i < 8; ++i) dd[i] = dot4(h0, ea[i]) + dot4(h1, eb[i]);
#pragma unroll
    for (int off = 32; off >= 1; off >>= 1) {
#pragma unroll
      for (int i = 0; i < 8; ++i) dd[i] += __shfl_xor(dd[i], off, 64);
    }
    float hm = dd[0];
#pragma unroll
    for (int i = 1; i < 8; ++i) hm = fmaxf(hm, dd[i]);
    const float mn = fmaxf(m, hm);
    const float sc = __expf(m - mn);
    float p[8], psum = 0.f;
#pragma unroll
    for (int i = 0; i < 8; ++i) { p[i] = __expf(dd[i] - mn); psum += p[i]; }
    lsum = lsum*sc + psum;
#pragma unroll
    for (int j = 0; j < 8; ++j) acc[j] *= sc;
#pragma unroll
    for (int i = 0; i < 8; ++i) {
      acc[0] += p[i]*ea[i].x; acc[1] += p[i]*ea[i].y;
      acc[2] += p[i]*ea[i].z; acc[3] += p[i]*ea[i].w;
      acc[4] += p[i]*eb[i].x; acc[5] += p[i]*eb[i].y;
      acc[6] += p[i]*eb[i].z; acc[7] += p[i]*eb[i].w;
    }
    m = mn;
  }

  __shared__ float sm4[4], sl4[4];
  __shared__ float sacc[4][HH];
  if (lane == 0) { sm4[w] = m; sl4[w] = lsum; }
  __syncthreads();
  const float M = fmaxf(fmaxf(sm4[0], sm4[1]), fmaxf(sm4[2], sm4[3]));
  const float ew = __expf(m - M);
#pragma unroll
  for (int j = 0; j < 8; ++j) sacc[w][lane*8 + j] = acc[j]*ew;
  __syncthreads();

  const int rec = blockIdx.x;
  for (int hh = t; hh < HH; hh += 256)
    pacc[(size_t)rec*HH + hh] = sacc[0][hh]+sacc[1][hh]+sacc[2][hh]+sacc[3][hh];
  if (t == 0) {
    float L = sl4[0]*__expf(sm4[0]-M) + sl4[1]*__expf(sm4[1]-M)
            + sl4[2]*__expf(sm4[2]-M) + sl4[3]*__expf(sm4[3]-M);
    pm[rec] = M; pl[rec] = L;
  }
}

// ---------------------------------------------------------------------------
// Kernel B: combine NSPLIT partials per b -> context -> featA (fragment order)
// ---------------------------------------------------------------------------
__global__ __launch_bounds__(256) void attn_reduce(
    const float* __restrict__ pm, const float* __restrict__ pl,
    const float* __restrict__ pacc, __hip_bfloat16* __restrict__ featA)
{
  const int b = blockIdx.x, t = threadIdx.x;
  __shared__ float smm[NSPLIT], sll[NSPLIT], sco[NSPLIT];
  if (t < NSPLIT) { smm[t] = pm[b*NSPLIT + t]; sll[t] = pl[b*NSPLIT + t]; }
  __syncthreads();
  float M = -INFINITY;
  for (int q = 0; q < NSPLIT; ++q) M = fmaxf(M, smm[q]);
  float L = 0.f;
  for (int q = 0; q < NSPLIT; ++q) L += sll[q]*__expf(smm[q]-M);
  const float inv = 1.f/L;
  if (t < NSPLIT) sco[t] = __expf(smm[t]-M)*inv;
  __syncthreads();
  const int hh0 = 2*t;
  float s0 = 0.f, s1 = 0.f;
  for (int q = 0; q < NSPLIT; ++q) {
    const float* pq = pacc + ((size_t)b*NSPLIT + q)*HH;
    s0 += pq[hh0]   * sco[q];
    s1 += pq[hh0+1] * sco[q];
  }
  const size_t a = fragAddr(b, HH + hh0);
  featA[a]   = (__hip_bfloat16)s0;
  featA[a+1] = (__hip_bfloat16)s1;
}

// ---------------------------------------------------------------------------
// Kernel C: GRU gates GEMM, K-split x4 -> 288 blocks.
// ---------------------------------------------------------------------------
__global__ __launch_bounds__(256) void gru_gemm(
    const int* __restrict__ last_out, const float* __restrict__ emb,
    const float* __restrict__ hprev, const __hip_bfloat16* __restrict__ featA,
    const float* __restrict__ W_ih, const float* __restrict__ W_hh,
    float* __restrict__ gates)
{
  const int u = blockIdx.x;
  const int gt = u / 12;
  const int rem = u % 12;
  const int seg = rem >> 2, ks = rem & 3;
  const int w = threadIdx.x >> 6, lane = threadIdx.x & 63;
  const int col = lane & 15, kg = lane >> 4;
  const int g = gt*64 + w*16 + col;

  const float* wrow = (seg == 2) ? (W_hh + (size_t)g*HH)
                                 : (W_ih + (size_t)g*KD + seg*HH);
  int lo_r[4];
#pragma unroll
  for (int mt = 0; mt < 4; ++mt) lo_r[mt] = last_out[mt*16 + col];

  f32x4 acc[4];
#pragma unroll
  for (int mt = 0; mt < 4; ++mt) acc[mt] = (f32x4){0.f,0.f,0.f,0.f};

  const int kbeg = ks*128, kend = kbeg + 128;
  for (int k0 = kbeg; k0 < kend; k0 += 32) {
    const float* wp = wrow + k0 + kg*8;
    const bf16x8 bf = cvt8(*(const float4*)wp, *(const float4*)(wp+4));
#pragma unroll
    for (int mt = 0; mt < 4; ++mt) {
      const int bb = mt*16 + col;
      bf16x8 af;
      if (seg == 0) {
        const float* ap = emb + (size_t)lo_r[mt]*HH + k0 + kg*8;
        af = cvt8(*(const float4*)ap, *(const float4*)(ap+4));
      } else if (seg == 1) {
        af = *(const bf16x8*)(featA + fragAddr(bb, HH + k0 + kg*8));
      } else {
        const float* ap = hprev + (size_t)bb*HH + k0 + kg*8;
        af = cvt8(*(const float4*)ap, *(const float4*)(ap+4));
      }
      acc[mt] = __builtin_amdgcn_mfma_f32_16x16x32_bf16(af, bf, acc[mt], 0, 0, 0);
    }
  }

  float* gp = gates + (size_t)rem*BB*1536;
#pragma unroll
  for (int mt = 0; mt < 4; ++mt)
#pragma unroll
    for (int reg = 0; reg < 4; ++reg) {
      const int brow = mt*16 + kg*4 + reg;
      gp[(size_t)brow*1536 + g] = acc[mt][reg];
    }
}

// ---------------------------------------------------------------------------
// Kernel C2: GRU pointwise, sums 12 partials.
// ---------------------------------------------------------------------------
__global__ __launch_bounds__(512) void gru_pointwise(
    const float* __restrict__ gates, const float* __restrict__ hprev,
    const float* __restrict__ b_ih, const float* __restrict__ b_hh,
    float* __restrict__ hid_out, __hip_bfloat16* __restrict__ featA)
{
  const int b = blockIdx.x, j = threadIdx.x;

  float i_r = 0.f, i_z = 0.f, i_n = 0.f;
#pragma unroll
  for (int p = 0; p < 8; ++p) {
    const float* gp = gates + ((size_t)p*BB + b)*1536;
    i_r += gp[j]; i_z += gp[HH + j]; i_n += gp[2*HH + j];
  }
  float h_r = 0.f, h_z = 0.f, h_n = 0.f;
#pragma unroll
  for (int p = 8; p < 12; ++p) {
    const float* gp = gates + ((size_t)p*BB + b)*1536;
    h_r += gp[j]; h_z += gp[HH + j]; h_n += gp[2*HH + j];
  }

  const float r = 1.f/(1.f + __expf(-(i_r + h_r + b_ih[j] + b_hh[j])));
  const float z = 1.f/(1.f + __expf(-(i_z + h_z + b_ih[HH+j] + b_hh[HH+j])));
  const float n = tanhf(i_n + b_ih[2*HH+j] + r*(h_n + b_hh[2*HH+j]));
  const float hp = hprev[b*HH + j];
  const float hn = (1.f - z)*n + z*hp;
  hid_out[b*HH + j] = hn;
  featA[fragAddr(b, j)] = (__hip_bfloat16)hn;
}

// ---------------------------------------------------------------------------
// Kernel D1: logits GEMM partials, K-split x2 -> 1572 blocks (6.1/CU).
// Single-buffered 16KB DMA-staged W tile (both-sides XOR swizzle, rule #21).
// Block-level TLP (6+ resident blocks/CU) hides HBM latency instead of the
// VGPR-hungry register pipelines (R17/R18) or 2-buffer barrier drain (R19).
// ---------------------------------------------------------------------------
__global__ __launch_bounds__(256, 4) void gemm_ks(
    const __hip_bfloat16* __restrict__ featA, const float* __restrict__ W_out,
    float* __restrict__ partial)
{
  __shared__ float wtile[4096];        // 16 KB
  const int bid = blockIdx.x;
  const int tile = bid >> 1, half = bid & 1;
  const int t = threadIdx.x;
  const int w = t >> 6, lane = t & 63;
  const int col = lane & 15, kg = lane >> 4;
  const int vbase = tile*64;
  const int rowL = w*16 + col;
  const int sXor = (rowL & 7) << 2;

  const __hip_bfloat16* fp = featA + (size_t)half*16*2048 + lane*8;

  auto stage = [&](int kc) {
#pragma unroll
    for (int i = 0; i < 4; ++i) {
      const int sigma = (w*4 + i)*64 + lane;      // 16B slot index
      const int row = sigma >> 4;
      const int t16 = sigma & 15;
      const int kdl = (t16*4) ^ ((row & 7) << 2); // inverse-swizzled k (dwords)
      int grow = vbase + row; if (grow > VV-1) grow = VV-1;
      const float* src = W_out + (size_t)grow*KD + half*512 + kc*64 + kdl;
      __builtin_amdgcn_global_load_lds((glb_void*)src,
          (lds_void*)(wtile + (w*4 + i)*256), 16, 0, 0);
    }
  };

  f32x4 acc[4];
#pragma unroll
  for (int mt = 0; mt < 4; ++mt) acc[mt] = (f32x4){0.f,0.f,0.f,0.f};

#pragma unroll 1
  for (int kc = 0; kc < 8; ++kc) {
    stage(kc);
    __syncthreads();                    // vmcnt(0) drain: DMA complete
#pragma unroll
    for (int h = 0; h < 2; ++h) {
      const int kin = h*32 + kg*8;
      const float4 wa = *(const float4*)(wtile + rowL*64 + (kin ^ sXor));
      const float4 wb = *(const float4*)(wtile + rowL*64 + ((kin + 4) ^ sXor));
      const bf16x8 bf = cvt8(wa, wb);
      const __hip_bfloat16* f = fp + (size_t)(kc*2 + h)*2048;
      acc[0] = __builtin_amdgcn_mfma_f32_16x16x32_bf16(*(const bf16x8*)(f),        bf, acc[0], 0, 0, 0);
      acc[1] = __builtin_amdgcn_mfma_f32_16x16x32_bf16(*(const bf16x8*)(f + 512),  bf, acc[1], 0, 0, 0);
      acc[2] = __builtin_amdgcn_mfma_f32_16x16x32_bf16(*(const bf16x8*)(f + 1024), bf, acc[2], 0, 0, 0);
      acc[3] = __builtin_amdgcn_mfma_f32_16x16x32_bf16(*(const bf16x8*)(f + 1536), bf, acc[3], 0, 0, 0);
    }
    __syncthreads();                    // WAR guard before next stage
  }

  float* pout = partial + (size_t)bid*4096;
#pragma unroll
  for (int mt = 0; mt < 4; ++mt)
#pragma unroll
    for (int reg = 0; reg < 4; ++reg) {
      const int brow = mt*16 + kg*4 + reg;
      pout[brow*64 + w*16 + col] = acc[mt][reg];
    }
}

// ---------------------------------------------------------------------------
// Kernel D2: combine K-split halves + bias -> logits, fused lsm partials.
// ---------------------------------------------------------------------------
__global__ __launch_bounds__(256) void combine(
    const float* __restrict__ partial, const float* __restrict__ b_out,
    float* __restrict__ out, float* __restrict__ pmE, float* __restrict__ plE)
{
  __shared__ float vals[64*65];
  __shared__ float pMq[4*64], pLq[4*64];
  const int tile = blockIdx.x;
  const int t = threadIdx.x;
  const int vbase = tile*64;
  const float* p0 = partial + (size_t)(tile*2 + 0)*4096;
  const float* p1 = partial + (size_t)(tile*2 + 1)*4096;

#pragma unroll
  for (int j = 0; j < 4; ++j) {
    const int i = t*16 + j*4;
    const float4 f0 = *(const float4*)(p0 + i);
    const float4 f1 = *(const float4*)(p1 + i);
    const int brow = i >> 6, vcol = i & 63;
#pragma unroll
    for (int e = 0; e < 4; ++e) {
      const int v = vbase + vcol + e;
      const float pe = (e==0 ? f0.x+f1.x : e==1 ? f0.y+f1.y : e==2 ? f0.z+f1.z : f0.w+f1.w);
      if (v < VV) {
        const float val = pe + b_out[v];
        out[(size_t)brow*VV + v] = val;
        vals[brow*65 + vcol + e] = val;
      } else {
        vals[brow*65 + vcol + e] = -INFINITY;
      }
    }
  }
  __syncthreads();

  // two-stage lsm partial with empty-quadrant guards
  {
    const int row = t & 63, q = t >> 6;
    const float* vr = vals + row*65 + q*16;
    float M = -INFINITY;
#pragma unroll
    for (int i = 0; i < 16; ++i) M = fmaxf(M, vr[i]);
    float L = 0.f;
    if (M > -INFINITY) {
#pragma unroll
      for (int i = 0; i < 16; ++i) L += __expf(vr[i] - M);
    }
    pMq[q*64 + row] = M; pLq[q*64 + row] = L;
  }
  __syncthreads();
  if (t < 64) {
    float M = pMq[t], L = pLq[t];   // q=0 always has valid col 0
#pragma unroll
    for (int q = 1; q < 4; ++q) {
      const float mq = pMq[q*64 + t], lq = pLq[q*64 + t];
      if (mq > -INFINITY) {
        const float mn = fmaxf(M, mq);
        L = L*__expf(M - mn) + lq*__expf(mq - mn);
        M = mn;
      }
    }
    pmE[t*1024 + tile] = M; plE[t*1024 + tile] = L;
  }
}

// ---------------------------------------------------------------------------
// Kernel E: fused row-reduce + subtract.
// ---------------------------------------------------------------------------
__global__ __launch_bounds__(256) void lsm_sub(
    float* __restrict__ out, const float* __restrict__ pmE,
    const float* __restrict__ plE)
{
  const int t = threadIdx.x;
  const int wv = t >> 6, lane = t & 63;
  const size_t off = (size_t)blockIdx.x * 1024;
  const size_t total = (size_t)BB*VV;
  __shared__ float cs[2];
  __shared__ int rowA_s;

  if (wv < 2) {
    size_t pos = (wv == 0) ? off : (off + 1023 < total ? off + 1023 : total - 1);
    const int row = (int)(pos / VV);
    float M = -INFINITY, L = 0.f;
    for (int q = lane; q < NTILE; q += 64) {
      const float mq = pmE[row*1024 + q], lq = plE[row*1024 + q];
      const float mn = fmaxf(M, mq);
      L = L*__expf(M - mn) + lq*__expf(mq - mn);
      M = mn;
    }
#pragma unroll
    for (int o = 32; o >= 1; o >>= 1) {
      const float m2 = __shfl_xor(M, o, 64), l2 = __shfl_xor(L, o, 64);
      const float mn = fmaxf(M, m2);
      L = L*__expf(M - mn) + l2*__expf(m2 - mn);
      M = mn;
    }
    if (lane == 0) {
      cs[wv] = M + logf(L);
      if (wv == 0) rowA_s = row;
    }
  }
  __syncthreads();

  const size_t i = off + (size_t)t*4;
  if (i >= total) return;
  const size_t rs = (size_t)(rowA_s + 1)*VV;
  float4 v = *(float4*)(out + i);
  v.x -= (i     >= rs) ? cs[1] : cs[0];
  v.y -= (i + 1 >= rs) ? cs[1] : cs[0];
  v.z -= (i + 2 >= rs) ? cs[1] : cs[0];
  v.w -= (i + 3 >= rs) ? cs[1] : cs[0];
  *(float4*)(out + i) = v;
}

// ---------------------------------------------------------------------------
extern "C" void kernel_launch(void* const* d_in, const int* in_sizes, int n_in,
                              void* d_out, int out_size, void* d_ws, size_t ws_size,
                              hipStream_t stream)
{
  const int*   last_output = (const int*)d_in[0];
  const float* last_hidden = (const float*)d_in[1];
  const float* enc         = (const float*)d_in[2];
  const float* emb         = (const float*)d_in[3];
  const float* W_ih        = (const float*)d_in[4];
  const float* b_ih        = (const float*)d_in[5];
  const float* W_hh        = (const float*)d_in[6];
  const float* b_hh        = (const float*)d_in[7];
  const float* W_out       = (const float*)d_in[8];
  const float* b_out       = (const float*)d_in[9];
  float* out = (float*)d_out;

  __hip_bfloat16* featA = (__hip_bfloat16*)d_ws;            // 128 KB
  float* gates = (float*)((char*)d_ws + 131072);            // 12x64x1536 f32 = 4.7 MB
  float* pm    = gates + (size_t)12*BB*1536;                // 2048
  float* pl    = pm + BB*NSPLIT;                            // 2048
  float* pmE   = pl + BB*NSPLIT;                            // 64*1024
  float* plE   = pmE + BB*1024;                             // 64*1024
  float* partial = plE + BB*1024;                           // 1572*4096 f32 = 25.8 MB
  float* pacc = out;   // 4 MB parked in dead logits region
  float* hid_out = out + (size_t)BB*VV;

  attn_partial <<<dim3(BB*NSPLIT), dim3(256), 0, stream>>>(last_hidden, enc, pm, pl, pacc);
  attn_reduce  <<<dim3(BB),        dim3(256), 0, stream>>>(pm, pl, pacc, featA);
  gru_gemm     <<<dim3(24*12),     dim3(256), 0, stream>>>(last_output, emb, last_hidden,
                                                           featA, W_ih, W_hh, gates);
  gru_pointwise<<<dim3(BB),        dim3(512), 0, stream>>>(gates, last_hidden, b_ih, b_hh,
                                                           hid_out, featA);
  gemm_ks      <<<dim3(NTILE*2),   dim3(256), 0, stream>>>(featA, W_out, partial);
  combine      <<<dim3(NTILE),     dim3(256), 0, stream>>>(partial, b_out, out, pmE, plE);
  lsm_sub      <<<dim3((int)(((size_t)BB*VV + 1023)/1024)), dim3(256), 0, stream>>>(out, pmE, plE);
}

// Round 21
// 157.900 us; speedup vs baseline: 1.1855x; 1.1855x over previous
//
#include <hip/hip_runtime.h>
#include <hip/hip_bf16.h>
#include <math.h>

#define BB 64
#define SS 2048
#define HH 512
#define VV 50257
#define KD 1024    // I + H
#define NSPLIT 32  // attn s-chunks per batch row
#define NTILE 786  // ceil(VV/64)

typedef float f32x4 __attribute__((ext_vector_type(4)));
typedef __bf16 bf16x8 __attribute__((ext_vector_type(8)));
typedef __attribute__((address_space(3))) void lds_void;
typedef __attribute__((address_space(1))) const void glb_void;

__device__ __forceinline__ float dot4(float4 a, float4 b) {
  return a.x*b.x + a.y*b.y + a.z*b.z + a.w*b.w;
}

__device__ __forceinline__ bf16x8 cvt8(float4 a, float4 b) {
  bf16x8 r;
  r[0]=(__bf16)a.x; r[1]=(__bf16)a.y; r[2]=(__bf16)a.z; r[3]=(__bf16)a.w;
  r[4]=(__bf16)b.x; r[5]=(__bf16)b.y; r[6]=(__bf16)b.z; r[7]=(__bf16)b.w;
  return r;
}

// featA fragment-linear layout: element (b, k) lives at
//   (k>>5)*2048 + (b>>4)*512 + ((k>>3)&3)*128 + (b&15)*8 + (k&7)
__device__ __forceinline__ size_t fragAddr(int b, int k) {
  return (size_t)(k >> 5)*2048 + (size_t)(b >> 4)*512
       + (size_t)((k >> 3) & 3)*128 + (size_t)(b & 15)*8 + (size_t)(k & 7);
}

// ---------------------------------------------------------------------------
// Kernel A: attention partials (R14 proven; R15-measured ~44us).
// ---------------------------------------------------------------------------
__global__ __launch_bounds__(256) void attn_partial(
    const float* __restrict__ hprev, const float* __restrict__ enc,
    float* __restrict__ pm, float* __restrict__ pl, float* __restrict__ pacc)
{
  const int b = blockIdx.x >> 5;
  const int split = blockIdx.x & 31;
  const int t = threadIdx.x;
  const int w = t >> 6, lane = t & 63;

  const float* hb = hprev + b*HH + lane*8;
  const float4 h0 = *(const float4*)hb;
  const float4 h1 = *(const float4*)(hb + 4);
  const int s0 = split*64 + w*16;

  float m = -INFINITY, lsum = 0.f;
  float acc[8];
#pragma unroll
  for (int j = 0; j < 8; ++j) acc[j] = 0.f;

#pragma unroll 1
  for (int half = 0; half < 2; ++half) {
    float4 ea[8], eb[8];
#pragma unroll
    for (int i = 0; i < 8; ++i) {
      const float* ep = enc + ((size_t)(s0 + half*8 + i)*BB + b)*HH + lane*8;
      ea[i] = *(const float4*)ep; eb[i] = *(const float4*)(ep + 4);
    }
    float dd[8];
#pragma unroll
    for (int i = 0; i < 8; ++i) dd[i] = dot4(h0, ea[i]) + dot4(h1, eb[i]);
#pragma unroll
    for (int off = 32; off >= 1; off >>= 1) {
#pragma unroll
      for (int i = 0; i < 8; ++i) dd[i] += __shfl_xor(dd[i], off, 64);
    }
    float hm = dd[0];
#pragma unroll
    for (int i = 1; i < 8; ++i) hm = fmaxf(hm, dd[i]);
    const float mn = fmaxf(m, hm);
    const float sc = __expf(m - mn);
    float p[8], psum = 0.f;
#pragma unroll
    for (int i = 0; i < 8; ++i) { p[i] = __expf(dd[i] - mn); psum += p[i]; }
    lsum = lsum*sc + psum;
#pragma unroll
    for (int j = 0; j < 8; ++j) acc[j] *= sc;
#pragma unroll
    for (int i = 0; i < 8; ++i) {
      acc[0] += p[i]*ea[i].x; acc[1] += p[i]*ea[i].y;
      acc[2] += p[i]*ea[i].z; acc[3] += p[i]*ea[i].w;
      acc[4] += p[i]*eb[i].x; acc[5] += p[i]*eb[i].y;
      acc[6] += p[i]*eb[i].z; acc[7] += p[i]*eb[i].w;
    }
    m = mn;
  }

  __shared__ float sm4[4], sl4[4];
  __shared__ float sacc[4][HH];
  if (lane == 0) { sm4[w] = m; sl4[w] = lsum; }
  __syncthreads();
  const float M = fmaxf(fmaxf(sm4[0], sm4[1]), fmaxf(sm4[2], sm4[3]));
  const float ew = __expf(m - M);
#pragma unroll
  for (int j = 0; j < 8; ++j) sacc[w][lane*8 + j] = acc[j]*ew;
  __syncthreads();

  const int rec = blockIdx.x;
  for (int hh = t; hh < HH; hh += 256)
    pacc[(size_t)rec*HH + hh] = sacc[0][hh]+sacc[1][hh]+sacc[2][hh]+sacc[3][hh];
  if (t == 0) {
    float L = sl4[0]*__expf(sm4[0]-M) + sl4[1]*__expf(sm4[1]-M)
            + sl4[2]*__expf(sm4[2]-M) + sl4[3]*__expf(sm4[3]-M);
    pm[rec] = M; pl[rec] = L;
  }
}

// ---------------------------------------------------------------------------
// Kernel B: combine NSPLIT partials per b -> context -> featA (fragment order)
// ---------------------------------------------------------------------------
__global__ __launch_bounds__(256) void attn_reduce(
    const float* __restrict__ pm, const float* __restrict__ pl,
    const float* __restrict__ pacc, __hip_bfloat16* __restrict__ featA)
{
  const int b = blockIdx.x, t = threadIdx.x;
  __shared__ float smm[NSPLIT], sll[NSPLIT], sco[NSPLIT];
  if (t < NSPLIT) { smm[t] = pm[b*NSPLIT + t]; sll[t] = pl[b*NSPLIT + t]; }
  __syncthreads();
  float M = -INFINITY;
  for (int q = 0; q < NSPLIT; ++q) M = fmaxf(M, smm[q]);
  float L = 0.f;
  for (int q = 0; q < NSPLIT; ++q) L += sll[q]*__expf(smm[q]-M);
  const float inv = 1.f/L;
  if (t < NSPLIT) sco[t] = __expf(smm[t]-M)*inv;
  __syncthreads();
  const int hh0 = 2*t;
  float s0 = 0.f, s1 = 0.f;
  for (int q = 0; q < NSPLIT; ++q) {
    const float* pq = pacc + ((size_t)b*NSPLIT + q)*HH;
    s0 += pq[hh0]   * sco[q];
    s1 += pq[hh0+1] * sco[q];
  }
  const size_t a = fragAddr(b, HH + hh0);
  featA[a]   = (__hip_bfloat16)s0;
  featA[a+1] = (__hip_bfloat16)s1;
}

// ---------------------------------------------------------------------------
// Kernel C: GRU gates GEMM, K-split x4 -> 288 blocks.
// ---------------------------------------------------------------------------
__global__ __launch_bounds__(256) void gru_gemm(
    const int* __restrict__ last_out, const float* __restrict__ emb,
    const float* __restrict__ hprev, const __hip_bfloat16* __restrict__ featA,
    const float* __restrict__ W_ih, const float* __restrict__ W_hh,
    float* __restrict__ gates)
{
  const int u = blockIdx.x;
  const int gt = u / 12;
  const int rem = u % 12;
  const int seg = rem >> 2, ks = rem & 3;
  const int w = threadIdx.x >> 6, lane = threadIdx.x & 63;
  const int col = lane & 15, kg = lane >> 4;
  const int g = gt*64 + w*16 + col;

  const float* wrow = (seg == 2) ? (W_hh + (size_t)g*HH)
                                 : (W_ih + (size_t)g*KD + seg*HH);
  int lo_r[4];
#pragma unroll
  for (int mt = 0; mt < 4; ++mt) lo_r[mt] = last_out[mt*16 + col];

  f32x4 acc[4];
#pragma unroll
  for (int mt = 0; mt < 4; ++mt) acc[mt] = (f32x4){0.f,0.f,0.f,0.f};

  const int kbeg = ks*128, kend = kbeg + 128;
  for (int k0 = kbeg; k0 < kend; k0 += 32) {
    const float* wp = wrow + k0 + kg*8;
    const bf16x8 bf = cvt8(*(const float4*)wp, *(const float4*)(wp+4));
#pragma unroll
    for (int mt = 0; mt < 4; ++mt) {
      const int bb = mt*16 + col;
      bf16x8 af;
      if (seg == 0) {
        const float* ap = emb + (size_t)lo_r[mt]*HH + k0 + kg*8;
        af = cvt8(*(const float4*)ap, *(const float4*)(ap+4));
      } else if (seg == 1) {
        af = *(const bf16x8*)(featA + fragAddr(bb, HH + k0 + kg*8));
      } else {
        const float* ap = hprev + (size_t)bb*HH + k0 + kg*8;
        af = cvt8(*(const float4*)ap, *(const float4*)(ap+4));
      }
      acc[mt] = __builtin_amdgcn_mfma_f32_16x16x32_bf16(af, bf, acc[mt], 0, 0, 0);
    }
  }

  float* gp = gates + (size_t)rem*BB*1536;
#pragma unroll
  for (int mt = 0; mt < 4; ++mt)
#pragma unroll
    for (int reg = 0; reg < 4; ++reg) {
      const int brow = mt*16 + kg*4 + reg;
      gp[(size_t)brow*1536 + g] = acc[mt][reg];
    }
}

// ---------------------------------------------------------------------------
// Kernel C2: GRU pointwise, sums 12 partials.
// ---------------------------------------------------------------------------
__global__ __launch_bounds__(512) void gru_pointwise(
    const float* __restrict__ gates, const float* __restrict__ hprev,
    const float* __restrict__ b_ih, const float* __restrict__ b_hh,
    float* __restrict__ hid_out, __hip_bfloat16* __restrict__ featA)
{
  const int b = blockIdx.x, j = threadIdx.x;

  float i_r = 0.f, i_z = 0.f, i_n = 0.f;
#pragma unroll
  for (int p = 0; p < 8; ++p) {
    const float* gp = gates + ((size_t)p*BB + b)*1536;
    i_r += gp[j]; i_z += gp[HH + j]; i_n += gp[2*HH + j];
  }
  float h_r = 0.f, h_z = 0.f, h_n = 0.f;
#pragma unroll
  for (int p = 8; p < 12; ++p) {
    const float* gp = gates + ((size_t)p*BB + b)*1536;
    h_r += gp[j]; h_z += gp[HH + j]; h_n += gp[2*HH + j];
  }

  const float r = 1.f/(1.f + __expf(-(i_r + h_r + b_ih[j] + b_hh[j])));
  const float z = 1.f/(1.f + __expf(-(i_z + h_z + b_ih[HH+j] + b_hh[HH+j])));
  const float n = tanhf(i_n + b_ih[2*HH+j] + r*(h_n + b_hh[2*HH+j]));
  const float hp = hprev[b*HH + j];
  const float hn = (1.f - z)*n + z*hp;
  hid_out[b*HH + j] = hn;
  featA[fragAddr(b, j)] = (__hip_bfloat16)hn;
}

// ---------------------------------------------------------------------------
// Kernel D: logits GEMM (+bias) -> out, fused lsm partials.
// DMA double-buffered W staging with SMALL chunks (8 KB = 32 k), LDS 18.7 KB
// -> 6 resident blocks/CU (__launch_bounds__(256,6)). Aggregate in-flight
// DMA ~6x8KB = 48KB/CU: first config sized to the CU-level Little's law.
// Both-sides XOR swizzle (proven R19): LDS dword (row,k) = row*32+(k^sXor),
// write side linear with inverse-swizzled global source.
// ---------------------------------------------------------------------------
__global__ __launch_bounds__(256, 6) void logits_gemm(
    const __hip_bfloat16* __restrict__ featA, const float* __restrict__ W_out,
    const float* __restrict__ b_out, float* __restrict__ out,
    float* __restrict__ pmE, float* __restrict__ plE)
{
  __shared__ float smem[4672];   // wtile[2][2048] (16KB); vals(4160)+pMq/pLq union
  const int tile = blockIdx.x;
  const int t = threadIdx.x;
  const int w = t >> 6, lane = t & 63;
  const int col = lane & 15, kg = lane >> 4;
  const int vbase = tile*64;
  const int v = vbase + w*16 + col;
  const int rowL = w*16 + col;
  const int sXor = (rowL & 7) << 2;

  const __hip_bfloat16* fp = featA + lane*8;

  // stage one 64x32 f32 chunk (8 KB): 2 DMA instrs per thread
  auto stage = [&](int buf, int kc) {
#pragma unroll
    for (int i = 0; i < 2; ++i) {
      const int sigma = (w*2 + i)*64 + lane;      // 16B slot index, 0..511
      const int row = sigma >> 3;                 // 8 slots (32 dwords) per row
      const int t16 = sigma & 7;
      const int kdl = (t16*4) ^ ((row & 7) << 2); // inverse-swizzled k (dwords)
      int grow = vbase + row; if (grow > VV-1) grow = VV-1;
      const float* src = W_out + (size_t)grow*KD + kc*32 + kdl;
      __builtin_amdgcn_global_load_lds((glb_void*)src,
          (lds_void*)(smem + buf*2048 + (w*2 + i)*256), 16, 0, 0);
    }
  };

  f32x4 acc[4];
#pragma unroll
  for (int mt = 0; mt < 4; ++mt) acc[mt] = (f32x4){0.f,0.f,0.f,0.f};

  int buf = 0;
  stage(0, 0);
  __syncthreads();

#pragma unroll 1
  for (int kc = 0; kc < 32; ++kc) {
    if (kc + 1 < 32) stage(buf ^ 1, kc + 1);
    const float* wt = smem + buf*2048;
    const int kin = kg*8;
    const float4 wa = *(const float4*)(wt + rowL*32 + (kin ^ sXor));
    const float4 wb = *(const float4*)(wt + rowL*32 + ((kin + 4) ^ sXor));
    const bf16x8 bf = cvt8(wa, wb);
    const __hip_bfloat16* f = fp + (size_t)kc*2048;
    acc[0] = __builtin_amdgcn_mfma_f32_16x16x32_bf16(*(const bf16x8*)(f),        bf, acc[0], 0, 0, 0);
    acc[1] = __builtin_amdgcn_mfma_f32_16x16x32_bf16(*(const bf16x8*)(f + 512),  bf, acc[1], 0, 0, 0);
    acc[2] = __builtin_amdgcn_mfma_f32_16x16x32_bf16(*(const bf16x8*)(f + 1024), bf, acc[2], 0, 0, 0);
    acc[3] = __builtin_amdgcn_mfma_f32_16x16x32_bf16(*(const bf16x8*)(f + 1536), bf, acc[3], 0, 0, 0);
    __syncthreads();
    buf ^= 1;
  }

  // epilogue: vals (stride 65) unions with the now-dead wtile region
  float* vals = smem;                 // 4160 floats
  float* pMq = smem + 4160;           // 256
  float* pLq = smem + 4416;           // 256
  const float bo = (v < VV) ? b_out[v] : 0.f;
#pragma unroll
  for (int mt = 0; mt < 4; ++mt)
#pragma unroll
    for (int reg = 0; reg < 4; ++reg) {
      const float val = acc[mt][reg] + bo;
      const int brow = mt*16 + kg*4 + reg;
      if (v < VV) out[(size_t)brow*VV + v] = val;
      vals[brow*65 + w*16 + col] = (v < VV) ? val : -INFINITY;
    }
  __syncthreads();

  // two-stage lsm partial with empty-quadrant guards
  {
    const int row = t & 63, q = t >> 6;
    const float* vr = vals + row*65 + q*16;
    float M = -INFINITY;
#pragma unroll
    for (int i = 0; i < 16; ++i) M = fmaxf(M, vr[i]);
    float L = 0.f;
    if (M > -INFINITY) {
#pragma unroll
      for (int i = 0; i < 16; ++i) L += __expf(vr[i] - M);
    }
    pMq[q*64 + row] = M; pLq[q*64 + row] = L;
  }
  __syncthreads();
  if (t < 64) {
    float M = pMq[t], L = pLq[t];   // q=0 always has valid col 0
#pragma unroll
    for (int q = 1; q < 4; ++q) {
      const float mq = pMq[q*64 + t], lq = pLq[q*64 + t];
      if (mq > -INFINITY) {
        const float mn = fmaxf(M, mq);
        L = L*__expf(M - mn) + lq*__expf(mq - mn);
        M = mn;
      }
    }
    pmE[t*1024 + tile] = M; plE[t*1024 + tile] = L;
  }
}

// ---------------------------------------------------------------------------
// Kernel E: fused row-reduce + subtract.
// ---------------------------------------------------------------------------
__global__ __launch_bounds__(256) void lsm_sub(
    float* __restrict__ out, const float* __restrict__ pmE,
    const float* __restrict__ plE)
{
  const int t = threadIdx.x;
  const int wv = t >> 6, lane = t & 63;
  const size_t off = (size_t)blockIdx.x * 1024;
  const size_t total = (size_t)BB*VV;
  __shared__ float cs[2];
  __shared__ int rowA_s;

  if (wv < 2) {
    size_t pos = (wv == 0) ? off : (off + 1023 < total ? off + 1023 : total - 1);
    const int row = (int)(pos / VV);
    float M = -INFINITY, L = 0.f;
    for (int q = lane; q < NTILE; q += 64) {
      const float mq = pmE[row*1024 + q], lq = plE[row*1024 + q];
      const float mn = fmaxf(M, mq);
      L = L*__expf(M - mn) + lq*__expf(mq - mn);
      M = mn;
    }
#pragma unroll
    for (int o = 32; o >= 1; o >>= 1) {
      const float m2 = __shfl_xor(M, o, 64), l2 = __shfl_xor(L, o, 64);
      const float mn = fmaxf(M, m2);
      L = L*__expf(M - mn) + l2*__expf(m2 - mn);
      M = mn;
    }
    if (lane == 0) {
      cs[wv] = M + logf(L);
      if (wv == 0) rowA_s = row;
    }
  }
  __syncthreads();

  const size_t i = off + (size_t)t*4;
  if (i >= total) return;
  const size_t rs = (size_t)(rowA_s + 1)*VV;
  float4 v = *(float4*)(out + i);
  v.x -= (i     >= rs) ? cs[1] : cs[0];
  v.y -= (i + 1 >= rs) ? cs[1] : cs[0];
  v.z -= (i + 2 >= rs) ? cs[1] : cs[0];
  v.w -= (i + 3 >= rs) ? cs[1] : cs[0];
  *(float4*)(out + i) = v;
}

// ---------------------------------------------------------------------------
extern "C" void kernel_launch(void* const* d_in, const int* in_sizes, int n_in,
                              void* d_out, int out_size, void* d_ws, size_t ws_size,
                              hipStream_t stream)
{
  const int*   last_output = (const int*)d_in[0];
  const float* last_hidden = (const float*)d_in[1];
  const float* enc         = (const float*)d_in[2];
  const float* emb         = (const float*)d_in[3];
  const float* W_ih        = (const float*)d_in[4];
  const float* b_ih        = (const float*)d_in[5];
  const float* W_hh        = (const float*)d_in[6];
  const float* b_hh        = (const float*)d_in[7];
  const float* W_out       = (const float*)d_in[8];
  const float* b_out       = (const float*)d_in[9];
  float* out = (float*)d_out;

  __hip_bfloat16* featA = (__hip_bfloat16*)d_ws;            // 128 KB
  float* gates = (float*)((char*)d_ws + 131072);            // 12x64x1536 f32 = 4.7 MB
  float* pm   = gates + (size_t)12*BB*1536;                 // 2048
  float* pl   = pm + BB*NSPLIT;                             // 2048
  float* pmE  = pl + BB*NSPLIT;                             // 64*1024
  float* plE  = pmE + BB*1024;                              // 64*1024
  float* pacc = out;   // 4 MB parked in dead logits region
  float* hid_out = out + (size_t)BB*VV;

  attn_partial <<<dim3(BB*NSPLIT), dim3(256), 0, stream>>>(last_hidden, enc, pm, pl, pacc);
  attn_reduce  <<<dim3(BB),        dim3(256), 0, stream>>>(pm, pl, pacc, featA);
  gru_gemm     <<<dim3(24*12),     dim3(256), 0, stream>>>(last_output, emb, last_hidden,
                                                           featA, W_ih, W_hh, gates);
  gru_pointwise<<<dim3(BB),        dim3(512), 0, stream>>>(gates, last_hidden, b_ih, b_hh,
                                                           hid_out, featA);
  logits_gemm  <<<dim3(NTILE),     dim3(256), 0, stream>>>(featA, W_out, b_out, out, pmE, plE);
  lsm_sub      <<<dim3((int)(((size_t)BB*VV + 1023)/1024)), dim3(256), 0, stream>>>(out, pmE, plE);
}

// Round 22
// 153.376 us; speedup vs baseline: 1.2204x; 1.0295x over previous
//
#include <hip/hip_runtime.h>
#include <hip/hip_bf16.h>
#include <math.h>

#define BB 64
#define SS 2048
#define HH 512
#define VV 50257
#define KD 1024    // I + H
#define NSPLIT 32  // attn s-chunks per batch row
#define NTILE 786  // ceil(VV/64)

typedef float f32x4 __attribute__((ext_vector_type(4)));
typedef __bf16 bf16x8 __attribute__((ext_vector_type(8)));
typedef __attribute__((address_space(3))) void lds_void;
typedef __attribute__((address_space(1))) const void glb_void;

__device__ __forceinline__ float dot4(float4 a, float4 b) {
  return a.x*b.x + a.y*b.y + a.z*b.z + a.w*b.w;
}

__device__ __forceinline__ bf16x8 cvt8(float4 a, float4 b) {
  bf16x8 r;
  r[0]=(__bf16)a.x; r[1]=(__bf16)a.y; r[2]=(__bf16)a.z; r[3]=(__bf16)a.w;
  r[4]=(__bf16)b.x; r[5]=(__bf16)b.y; r[6]=(__bf16)b.z; r[7]=(__bf16)b.w;
  return r;
}

// featA fragment-linear layout: element (b, k) lives at
//   (k>>5)*2048 + (b>>4)*512 + ((k>>3)&3)*128 + (b&15)*8 + (k&7)
__device__ __forceinline__ size_t fragAddr(int b, int k) {
  return (size_t)(k >> 5)*2048 + (size_t)(b >> 4)*512
       + (size_t)((k >> 3) & 3)*128 + (size_t)(b & 15)*8 + (size_t)(k & 7);
}

// ---------------------------------------------------------------------------
// Kernel A: attention partials (R14 proven; R15-measured ~44us).
// ---------------------------------------------------------------------------
__global__ __launch_bounds__(256) void attn_partial(
    const float* __restrict__ hprev, const float* __restrict__ enc,
    float* __restrict__ pm, float* __restrict__ pl, float* __restrict__ pacc)
{
  const int b = blockIdx.x >> 5;
  const int split = blockIdx.x & 31;
  const int t = threadIdx.x;
  const int w = t >> 6, lane = t & 63;

  const float* hb = hprev + b*HH + lane*8;
  const float4 h0 = *(const float4*)hb;
  const float4 h1 = *(const float4*)(hb + 4);
  const int s0 = split*64 + w*16;

  float m = -INFINITY, lsum = 0.f;
  float acc[8];
#pragma unroll
  for (int j = 0; j < 8; ++j) acc[j] = 0.f;

#pragma unroll 1
  for (int half = 0; half < 2; ++half) {
    float4 ea[8], eb[8];
#pragma unroll
    for (int i = 0; i < 8; ++i) {
      const float* ep = enc + ((size_t)(s0 + half*8 + i)*BB + b)*HH + lane*8;
      ea[i] = *(const float4*)ep; eb[i] = *(const float4*)(ep + 4);
    }
    float dd[8];
#pragma unroll
    for (int i = 0; i < 8; ++i) dd[i] = dot4(h0, ea[i]) + dot4(h1, eb[i]);
#pragma unroll
    for (int off = 32; off >= 1; off >>= 1) {
#pragma unroll
      for (int i = 0; i < 8; ++i) dd[i] += __shfl_xor(dd[i], off, 64);
    }
    float hm = dd[0];
#pragma unroll
    for (int i = 1; i < 8; ++i) hm = fmaxf(hm, dd[i]);
    const float mn = fmaxf(m, hm);
    const float sc = __expf(m - mn);
    float p[8], psum = 0.f;
#pragma unroll
    for (int i = 0; i < 8; ++i) { p[i] = __expf(dd[i] - mn); psum += p[i]; }
    lsum = lsum*sc + psum;
#pragma unroll
    for (int j = 0; j < 8; ++j) acc[j] *= sc;
#pragma unroll
    for (int i = 0; i < 8; ++i) {
      acc[0] += p[i]*ea[i].x; acc[1] += p[i]*ea[i].y;
      acc[2] += p[i]*ea[i].z; acc[3] += p[i]*ea[i].w;
      acc[4] += p[i]*eb[i].x; acc[5] += p[i]*eb[i].y;
      acc[6] += p[i]*eb[i].z; acc[7] += p[i]*eb[i].w;
    }
    m = mn;
  }

  __shared__ float sm4[4], sl4[4];
  __shared__ float sacc[4][HH];
  if (lane == 0) { sm4[w] = m; sl4[w] = lsum; }
  __syncthreads();
  const float M = fmaxf(fmaxf(sm4[0], sm4[1]), fmaxf(sm4[2], sm4[3]));
  const float ew = __expf(m - M);
#pragma unroll
  for (int j = 0; j < 8; ++j) sacc[w][lane*8 + j] = acc[j]*ew;
  __syncthreads();

  const int rec = blockIdx.x;
  for (int hh = t; hh < HH; hh += 256)
    pacc[(size_t)rec*HH + hh] = sacc[0][hh]+sacc[1][hh]+sacc[2][hh]+sacc[3][hh];
  if (t == 0) {
    float L = sl4[0]*__expf(sm4[0]-M) + sl4[1]*__expf(sm4[1]-M)
            + sl4[2]*__expf(sm4[2]-M) + sl4[3]*__expf(sm4[3]-M);
    pm[rec] = M; pl[rec] = L;
  }
}

// ---------------------------------------------------------------------------
// Kernel B: combine NSPLIT partials per b -> context -> featA (fragment order)
// ---------------------------------------------------------------------------
__global__ __launch_bounds__(256) void attn_reduce(
    const float* __restrict__ pm, const float* __restrict__ pl,
    const float* __restrict__ pacc, __hip_bfloat16* __restrict__ featA)
{
  const int b = blockIdx.x, t = threadIdx.x;
  __shared__ float smm[NSPLIT], sll[NSPLIT], sco[NSPLIT];
  if (t < NSPLIT) { smm[t] = pm[b*NSPLIT + t]; sll[t] = pl[b*NSPLIT + t]; }
  __syncthreads();
  float M = -INFINITY;
  for (int q = 0; q < NSPLIT; ++q) M = fmaxf(M, smm[q]);
  float L = 0.f;
  for (int q = 0; q < NSPLIT; ++q) L += sll[q]*__expf(smm[q]-M);
  const float inv = 1.f/L;
  if (t < NSPLIT) sco[t] = __expf(smm[t]-M)*inv;
  __syncthreads();
  const int hh0 = 2*t;
  float s0 = 0.f, s1 = 0.f;
  for (int q = 0; q < NSPLIT; ++q) {
    const float* pq = pacc + ((size_t)b*NSPLIT + q)*HH;
    s0 += pq[hh0]   * sco[q];
    s1 += pq[hh0+1] * sco[q];
  }
  const size_t a = fragAddr(b, HH + hh0);
  featA[a]   = (__hip_bfloat16)s0;
  featA[a+1] = (__hip_bfloat16)s1;
}

// ---------------------------------------------------------------------------
// Kernel C: GRU gates GEMM, K-split x4 -> 288 blocks.
// ---------------------------------------------------------------------------
__global__ __launch_bounds__(256) void gru_gemm(
    const int* __restrict__ last_out, const float* __restrict__ emb,
    const float* __restrict__ hprev, const __hip_bfloat16* __restrict__ featA,
    const float* __restrict__ W_ih, const float* __restrict__ W_hh,
    float* __restrict__ gates)
{
  const int u = blockIdx.x;
  const int gt = u / 12;
  const int rem = u % 12;
  const int seg = rem >> 2, ks = rem & 3;
  const int w = threadIdx.x >> 6, lane = threadIdx.x & 63;
  const int col = lane & 15, kg = lane >> 4;
  const int g = gt*64 + w*16 + col;

  const float* wrow = (seg == 2) ? (W_hh + (size_t)g*HH)
                                 : (W_ih + (size_t)g*KD + seg*HH);
  int lo_r[4];
#pragma unroll
  for (int mt = 0; mt < 4; ++mt) lo_r[mt] = last_out[mt*16 + col];

  f32x4 acc[4];
#pragma unroll
  for (int mt = 0; mt < 4; ++mt) acc[mt] = (f32x4){0.f,0.f,0.f,0.f};

  const int kbeg = ks*128, kend = kbeg + 128;
  for (int k0 = kbeg; k0 < kend; k0 += 32) {
    const float* wp = wrow + k0 + kg*8;
    const bf16x8 bf = cvt8(*(const float4*)wp, *(const float4*)(wp+4));
#pragma unroll
    for (int mt = 0; mt < 4; ++mt) {
      const int bb = mt*16 + col;
      bf16x8 af;
      if (seg == 0) {
        const float* ap = emb + (size_t)lo_r[mt]*HH + k0 + kg*8;
        af = cvt8(*(const float4*)ap, *(const float4*)(ap+4));
      } else if (seg == 1) {
        af = *(const bf16x8*)(featA + fragAddr(bb, HH + k0 + kg*8));
      } else {
        const float* ap = hprev + (size_t)bb*HH + k0 + kg*8;
        af = cvt8(*(const float4*)ap, *(const float4*)(ap+4));
      }
      acc[mt] = __builtin_amdgcn_mfma_f32_16x16x32_bf16(af, bf, acc[mt], 0, 0, 0);
    }
  }

  float* gp = gates + (size_t)rem*BB*1536;
#pragma unroll
  for (int mt = 0; mt < 4; ++mt)
#pragma unroll
    for (int reg = 0; reg < 4; ++reg) {
      const int brow = mt*16 + kg*4 + reg;
      gp[(size_t)brow*1536 + g] = acc[mt][reg];
    }
}

// ---------------------------------------------------------------------------
// Kernel C2: GRU pointwise, sums 12 partials.
// ---------------------------------------------------------------------------
__global__ __launch_bounds__(512) void gru_pointwise(
    const float* __restrict__ gates, const float* __restrict__ hprev,
    const float* __restrict__ b_ih, const float* __restrict__ b_hh,
    float* __restrict__ hid_out, __hip_bfloat16* __restrict__ featA)
{
  const int b = blockIdx.x, j = threadIdx.x;

  float i_r = 0.f, i_z = 0.f, i_n = 0.f;
#pragma unroll
  for (int p = 0; p < 8; ++p) {
    const float* gp = gates + ((size_t)p*BB + b)*1536;
    i_r += gp[j]; i_z += gp[HH + j]; i_n += gp[2*HH + j];
  }
  float h_r = 0.f, h_z = 0.f, h_n = 0.f;
#pragma unroll
  for (int p = 8; p < 12; ++p) {
    const float* gp = gates + ((size_t)p*BB + b)*1536;
    h_r += gp[j]; h_z += gp[HH + j]; h_n += gp[2*HH + j];
  }

  const float r = 1.f/(1.f + __expf(-(i_r + h_r + b_ih[j] + b_hh[j])));
  const float z = 1.f/(1.f + __expf(-(i_z + h_z + b_ih[HH+j] + b_hh[HH+j])));
  const float n = tanhf(i_n + b_ih[2*HH+j] + r*(h_n + b_hh[2*HH+j]));
  const float hp = hprev[b*HH + j];
  const float hn = (1.f - z)*n + z*hp;
  hid_out[b*HH + j] = hn;
  featA[fragAddr(b, j)] = (__hip_bfloat16)hn;
}

// ---------------------------------------------------------------------------
// Kernel D: logits GEMM (+bias) -> out, fused lsm partials.
// T4 counted-vmcnt pipeline (m218 recipe): 2-buffer DMA staging, per chunk
//   s_waitcnt vmcnt(2)  [never 0 until last chunk]  -> raw s_barrier ->
//   compute -> raw s_barrier -> stage chunk+2 into freed buffer.
// Prefetch stays in flight ACROSS barriers (no compiler vmcnt(0) drain).
// Both-sides XOR swizzle (proven R19/R21). LDS 18.7 KB -> 6 blocks/CU.
// ---------------------------------------------------------------------------
__global__ __launch_bounds__(256, 6) void logits_gemm(
    const __hip_bfloat16* __restrict__ featA, const float* __restrict__ W_out,
    const float* __restrict__ b_out, float* __restrict__ out,
    float* __restrict__ pmE, float* __restrict__ plE)
{
  __shared__ float smem[4672];   // wtile[2][2048] (16KB); vals+pMq/pLq union
  const int tile = blockIdx.x;
  const int t = threadIdx.x;
  const int w = t >> 6, lane = t & 63;
  const int col = lane & 15, kg = lane >> 4;
  const int vbase = tile*64;
  const int v = vbase + w*16 + col;
  const int rowL = w*16 + col;
  const int sXor = (rowL & 7) << 2;

  const __hip_bfloat16* fp = featA + lane*8;

  // stage one 64x32 f32 chunk (8 KB): 2 DMA instrs per thread
  auto stage = [&](int buf, int kc) {
#pragma unroll
    for (int i = 0; i < 2; ++i) {
      const int sigma = (w*2 + i)*64 + lane;      // 16B slot index, 0..511
      const int row = sigma >> 3;                 // 8 slots (32 dwords) per row
      const int t16 = sigma & 7;
      const int kdl = (t16*4) ^ ((row & 7) << 2); // inverse-swizzled k (dwords)
      int grow = vbase + row; if (grow > VV-1) grow = VV-1;
      const float* src = W_out + (size_t)grow*KD + kc*32 + kdl;
      __builtin_amdgcn_global_load_lds((glb_void*)src,
          (lds_void*)(smem + buf*2048 + (w*2 + i)*256), 16, 0, 0);
    }
  };

  f32x4 acc[4];
#pragma unroll
  for (int mt = 0; mt < 4; ++mt) acc[mt] = (f32x4){0.f,0.f,0.f,0.f};

  stage(0, 0);
  stage(1, 1);          // 4 loads outstanding

#pragma unroll 1
  for (int kc = 0; kc < 32; ++kc) {
    if (kc < 31) asm volatile("s_waitcnt vmcnt(2)" ::: "memory");
    else         asm volatile("s_waitcnt vmcnt(0)" ::: "memory");
    __builtin_amdgcn_sched_barrier(0);
    __builtin_amdgcn_s_barrier();      // all waves' chunk-kc loads landed

    const float* wt = smem + (kc & 1)*2048;
    const int kin = kg*8;
    const float4 wa = *(const float4*)(wt + rowL*32 + (kin ^ sXor));
    const float4 wb = *(const float4*)(wt + rowL*32 + ((kin + 4) ^ sXor));
    const bf16x8 bf = cvt8(wa, wb);
    const __hip_bfloat16* f = fp + (size_t)kc*2048;
    acc[0] = __builtin_amdgcn_mfma_f32_16x16x32_bf16(*(const bf16x8*)(f),        bf, acc[0], 0, 0, 0);
    acc[1] = __builtin_amdgcn_mfma_f32_16x16x32_bf16(*(const bf16x8*)(f + 512),  bf, acc[1], 0, 0, 0);
    acc[2] = __builtin_amdgcn_mfma_f32_16x16x32_bf16(*(const bf16x8*)(f + 1024), bf, acc[2], 0, 0, 0);
    acc[3] = __builtin_amdgcn_mfma_f32_16x16x32_bf16(*(const bf16x8*)(f + 1536), bf, acc[3], 0, 0, 0);

    __builtin_amdgcn_s_barrier();      // all waves done reading buf (kc&1)
    if (kc + 2 < 32) stage(kc & 1, kc + 2);
  }
  __syncthreads();                     // full fence before smem reuse

  // epilogue: vals (stride 65) unions with the now-dead wtile region
  float* vals = smem;                 // 4160 floats
  float* pMq = smem + 4160;           // 256
  float* pLq = smem + 4416;           // 256
  const float bo = (v < VV) ? b_out[v] : 0.f;
#pragma unroll
  for (int mt = 0; mt < 4; ++mt)
#pragma unroll
    for (int reg = 0; reg < 4; ++reg) {
      const float val = acc[mt][reg] + bo;
      const int brow = mt*16 + kg*4 + reg;
      if (v < VV) out[(size_t)brow*VV + v] = val;
      vals[brow*65 + w*16 + col] = (v < VV) ? val : -INFINITY;
    }
  __syncthreads();

  // two-stage lsm partial with empty-quadrant guards
  {
    const int row = t & 63, q = t >> 6;
    const float* vr = vals + row*65 + q*16;
    float M = -INFINITY;
#pragma unroll
    for (int i = 0; i < 16; ++i) M = fmaxf(M, vr[i]);
    float L = 0.f;
    if (M > -INFINITY) {
#pragma unroll
      for (int i = 0; i < 16; ++i) L += __expf(vr[i] - M);
    }
    pMq[q*64 + row] = M; pLq[q*64 + row] = L;
  }
  __syncthreads();
  if (t < 64) {
    float M = pMq[t], L = pLq[t];   // q=0 always has valid col 0
#pragma unroll
    for (int q = 1; q < 4; ++q) {
      const float mq = pMq[q*64 + t], lq = pLq[q*64 + t];
      if (mq > -INFINITY) {
        const float mn = fmaxf(M, mq);
        L = L*__expf(M - mn) + lq*__expf(mq - mn);
        M = mn;
      }
    }
    pmE[t*1024 + tile] = M; plE[t*1024 + tile] = L;
  }
}

// ---------------------------------------------------------------------------
// Kernel E: fused row-reduce + subtract.
// ---------------------------------------------------------------------------
__global__ __launch_bounds__(256) void lsm_sub(
    float* __restrict__ out, const float* __restrict__ pmE,
    const float* __restrict__ plE)
{
  const int t = threadIdx.x;
  const int wv = t >> 6, lane = t & 63;
  const size_t off = (size_t)blockIdx.x * 1024;
  const size_t total = (size_t)BB*VV;
  __shared__ float cs[2];
  __shared__ int rowA_s;

  if (wv < 2) {
    size_t pos = (wv == 0) ? off : (off + 1023 < total ? off + 1023 : total - 1);
    const int row = (int)(pos / VV);
    float M = -INFINITY, L = 0.f;
    for (int q = lane; q < NTILE; q += 64) {
      const float mq = pmE[row*1024 + q], lq = plE[row*1024 + q];
      const float mn = fmaxf(M, mq);
      L = L*__expf(M - mn) + lq*__expf(mq - mn);
      M = mn;
    }
#pragma unroll
    for (int o = 32; o >= 1; o >>= 1) {
      const float m2 = __shfl_xor(M, o, 64), l2 = __shfl_xor(L, o, 64);
      const float mn = fmaxf(M, m2);
      L = L*__expf(M - mn) + l2*__expf(m2 - mn);
      M = mn;
    }
    if (lane == 0) {
      cs[wv] = M + logf(L);
      if (wv == 0) rowA_s = row;
    }
  }
  __syncthreads();

  const size_t i = off + (size_t)t*4;
  if (i >= total) return;
  const size_t rs = (size_t)(rowA_s + 1)*VV;
  float4 v = *(float4*)(out + i);
  v.x -= (i     >= rs) ? cs[1] : cs[0];
  v.y -= (i + 1 >= rs) ? cs[1] : cs[0];
  v.z -= (i + 2 >= rs) ? cs[1] : cs[0];
  v.w -= (i + 3 >= rs) ? cs[1] : cs[0];
  *(float4*)(out + i) = v;
}

// ---------------------------------------------------------------------------
extern "C" void kernel_launch(void* const* d_in, const int* in_sizes, int n_in,
                              void* d_out, int out_size, void* d_ws, size_t ws_size,
                              hipStream_t stream)
{
  const int*   last_output = (const int*)d_in[0];
  const float* last_hidden = (const float*)d_in[1];
  const float* enc         = (const float*)d_in[2];
  const float* emb         = (const float*)d_in[3];
  const float* W_ih        = (const float*)d_in[4];
  const float* b_ih        = (const float*)d_in[5];
  const float* W_hh        = (const float*)d_in[6];
  const float* b_hh        = (const float*)d_in[7];
  const float* W_out       = (const float*)d_in[8];
  const float* b_out       = (const float*)d_in[9];
  float* out = (float*)d_out;

  __hip_bfloat16* featA = (__hip_bfloat16*)d_ws;            // 128 KB
  float* gates = (float*)((char*)d_ws + 131072);            // 12x64x1536 f32 = 4.7 MB
  float* pm   = gates + (size_t)12*BB*1536;                 // 2048
  float* pl   = pm + BB*NSPLIT;                             // 2048
  float* pmE  = pl + BB*NSPLIT;                             // 64*1024
  float* plE  = pmE + BB*1024;                              // 64*1024
  float* pacc = out;   // 4 MB parked in dead logits region
  float* hid_out = out + (size_t)BB*VV;

  attn_partial <<<dim3(BB*NSPLIT), dim3(256), 0, stream>>>(last_hidden, enc, pm, pl, pacc);
  attn_reduce  <<<dim3(BB),        dim3(256), 0, stream>>>(pm, pl, pacc, featA);
  gru_gemm     <<<dim3(24*12),     dim3(256), 0, stream>>>(last_output, emb, last_hidden,
                                                           featA, W_ih, W_hh, gates);
  gru_pointwise<<<dim3(BB),        dim3(512), 0, stream>>>(gates, last_hidden, b_ih, b_hh,
                                                           hid_out, featA);
  logits_gemm  <<<dim3(NTILE),     dim3(256), 0, stream>>>(featA, W_out, b_out, out, pmE, plE);
  lsm_sub      <<<dim3((int)(((size_t)BB*VV + 1023)/1024)), dim3(256), 0, stream>>>(out, pmE, plE);
}